// Round 9
// baseline (145.096 us; speedup 1.0000x reference)
//
#include <hip/hip_runtime.h>

// Selective scan as a chunked parallel scan over t (R7 algorithm, verified).
// x:(B,d,L) dA/dB:(B,d,L,n) C:(B,n,L) D:(d,) -> y:(B,d,L); B=64 d=384 L=197 n=16.
//
// R9: TLP-max schedule. Single-buffered fat dwordx4 register loads, no
// prefetch pipeline, no sched_barriers, VGPR capped so all 24 waves/CU that
// the grid provides are resident (copy-ubench structure: latency hidden by
// wave count). Compute per 16-step chunk: in-lane composes + DPP row_shr
// prefix + quad DPP reduce; 4 ds_swizzle for the carry; Cs in padded LDS.

#define B_   64
#define DIN  384
#define L_   197
#define N_   16
#define CSTR 20          // padded LDS stride for Cs (2-way max on b128 reads)
#define NCH  12          // full 16-step chunks (t=0..191); tail t=192..196

template<int CTRL>
__device__ __forceinline__ float dppmov(float src, float oldv) {
    return __int_as_float(__builtin_amdgcn_update_dpp(
        __float_as_int(oldv), __float_as_int(src), CTRL, 0xF, 0xF, false));
}
__device__ __forceinline__ float qsum(float p) {   // sum over 4-lane quad (VALU)
    p += __int_as_float(__builtin_amdgcn_update_dpp(0, __float_as_int(p), 0xB1, 0xF, 0xF, true));
    p += __int_as_float(__builtin_amdgcn_update_dpp(0, __float_as_int(p), 0x4E, 0xF, 0xF, true));
    return p;
}
__device__ __forceinline__ float bcast12q(float v) {
    // lane <- lane ((l & 0x13) | 0x0C): row's lane 12+q  (BitMode 0x193)
    return __int_as_float(__builtin_amdgcn_ds_swizzle(__float_as_int(v), 0x193));
}

__global__ __launch_bounds__(256, 6)
void ssm_tlp(const float* __restrict__ x, const float* __restrict__ dA,
             const float* __restrict__ dB, const float* __restrict__ C,
             const float* __restrict__ D, float* __restrict__ y)
{
    __shared__ __align__(16) float Cs[L_ * CSTR];   // Cs[t*20+n] = C[b,n,t]

    const int tid = threadIdx.x;
    const int b   = blockIdx.y;

    const float* Cg = C + (size_t)b * (N_ * L_);
    for (int i = tid; i < N_ * L_; i += 256) {
        const int n = i / L_;
        const int t = i - n * L_;
        Cs[t * CSTR + n] = Cg[i];
    }
    __syncthreads();

    const int lane = tid & 63;
    const int wav  = tid >> 6;
    const int row  = lane >> 4;        // chain within wave
    const int p    = lane & 15;
    const int p4   = p >> 2;           // t-quad
    const int q    = p & 3;            // n-quad

    const int d   = blockIdx.x * 16 + wav * 4 + row;
    const size_t bd = (size_t)b * DIN + d;

    const float* Arow = dA + bd * (size_t)(L_ * N_);
    const float* Brow = dB + bd * (size_t)(L_ * N_);
    const float* Xrow = x  + bd * L_;
    float*       Yrow = y  + bd * L_;
    const float  Dd   = D[d];
    const int laneAB  = p4 * 64 + q * 4;
    const float* CsQ  = Cs + q * 4;

    float hcx = 0.f, hcy = 0.f, hcz = 0.f, hcw = 0.f;   // carry h[n=q*4+e]

    float4 A0,A1,A2,A3, G0,G1,G2,G3;
    float  x0,x1,x2,x3;

#define LOADC(c) do { \
    const float* _a = Arow + (c)*256 + laneAB; \
    const float* _g = Brow + (c)*256 + laneAB; \
    A0 = *(const float4*)(_a +  0); A1 = *(const float4*)(_a + 16); \
    A2 = *(const float4*)(_a + 32); A3 = *(const float4*)(_a + 48); \
    G0 = *(const float4*)(_g +  0); G1 = *(const float4*)(_g + 16); \
    G2 = *(const float4*)(_g + 32); G3 = *(const float4*)(_g + 48); \
    const float* _x = Xrow + (c)*16 + p4*4; \
    x0 = _x[0]; x1 = _x[1]; x2 = _x[2]; x3 = _x[3]; \
} while (0)

#define LOADT() do { \
    const int _tb = 192 + p4*4; \
    const int _t0 = _tb   > 196 ? 196 : _tb; \
    const int _t1 = _tb+1 > 196 ? 196 : _tb+1; \
    const int _t2 = _tb+2 > 196 ? 196 : _tb+2; \
    const int _t3 = _tb+3 > 196 ? 196 : _tb+3; \
    A0 = *(const float4*)(Arow + _t0*16 + q*4); \
    A1 = *(const float4*)(Arow + _t1*16 + q*4); \
    A2 = *(const float4*)(Arow + _t2*16 + q*4); \
    A3 = *(const float4*)(Arow + _t3*16 + q*4); \
    G0 = *(const float4*)(Brow + _t0*16 + q*4); \
    G1 = *(const float4*)(Brow + _t1*16 + q*4); \
    G2 = *(const float4*)(Brow + _t2*16 + q*4); \
    G3 = *(const float4*)(Brow + _t3*16 + q*4); \
    x0 = Xrow[_t0]; x1 = Xrow[_t1]; x2 = Xrow[_t2]; x3 = Xrow[_t3]; \
} while (0)

#define SCANE(E) do { \
    G0.E *= x0; G1.E *= x1; G2.E *= x2; G3.E *= x3; \
    G1.E = fmaf(A1.E, G0.E, G1.E); A1.E *= A0.E; \
    G2.E = fmaf(A2.E, G1.E, G2.E); A2.E *= A1.E; \
    G3.E = fmaf(A3.E, G2.E, G3.E); A3.E *= A2.E; \
    float _ta = A3.E, _tv = G3.E; \
    { float _pa = dppmov<0x114>(_ta, 1.0f), _pb = dppmov<0x114>(_tv, 0.0f); \
      _tv = fmaf(_ta, _pb, _tv); _ta *= _pa; } \
    { float _pa = dppmov<0x118>(_ta, 1.0f), _pb = dppmov<0x118>(_tv, 0.0f); \
      _tv = fmaf(_ta, _pb, _tv); _ta *= _pa; } \
    const float _Ea = dppmov<0x114>(_ta, 1.0f); \
    const float _Eb = dppmov<0x114>(_tv, 0.0f); \
    const float _s  = fmaf(_Ea, hc##E, _Eb); \
    G0.E = fmaf(A0.E, _s, G0.E); \
    G1.E = fmaf(A1.E, _s, G1.E); \
    G2.E = fmaf(A2.E, _s, G2.E); \
    G3.E = fmaf(A3.E, _s, G3.E); \
} while (0)

#define YJ(j, tcj, yf) do { \
    const float4 _c4 = *(const float4*)(CsQ + (tcj)*CSTR); \
    float _yp = fmaf(G##j.x, _c4.x, fmaf(G##j.y, _c4.y, \
                 fmaf(G##j.z, _c4.z, G##j.w * _c4.w))); \
    _yp = qsum(_yp); \
    yf = fmaf(x##j, Dd, _yp); \
} while (0)

#define COMPUTE(c, TAIL) do { \
    SCANE(x); SCANE(y); SCANE(z); SCANE(w); \
    const int _t0s = (TAIL) ? (192 + p4*4) : ((c)*16 + p4*4); \
    int _c0 = _t0s, _c1 = _t0s+1, _c2 = _t0s+2, _c3 = _t0s+3; \
    if (TAIL) { _c0 = _c0>196?196:_c0; _c1 = _c1>196?196:_c1; \
                _c2 = _c2>196?196:_c2; _c3 = _c3>196?196:_c3; } \
    float _yf0,_yf1,_yf2,_yf3; \
    YJ(0, _c0, _yf0); YJ(1, _c1, _yf1); \
    YJ(2, _c2, _yf2); YJ(3, _c3, _yf3); \
    hcx = bcast12q(G3.x); hcy = bcast12q(G3.y); \
    hcz = bcast12q(G3.z); hcw = bcast12q(G3.w); \
    const float _ys = (q==0) ? _yf0 : (q==1) ? _yf1 : (q==2) ? _yf2 : _yf3; \
    if (!(TAIL) || p4 == 0 || (p4 == 1 && q == 0)) Yrow[_t0s + q] = _ys; \
} while (0)

#pragma unroll 1
    for (int c = 0; c < NCH; ++c) {
        LOADC(c);
        COMPUTE(c, 0);
    }
    LOADT();
    COMPUTE(0, 1);   // tail t=192..196

#undef COMPUTE
#undef YJ
#undef SCANE
#undef LOADT
#undef LOADC
}

extern "C" void kernel_launch(void* const* d_in, const int* in_sizes, int n_in,
                              void* d_out, int out_size, void* d_ws, size_t ws_size,
                              hipStream_t stream) {
    const float* x  = (const float*)d_in[0];
    const float* dA = (const float*)d_in[1];
    const float* dB = (const float*)d_in[2];
    const float* C  = (const float*)d_in[3];
    const float* D  = (const float*)d_in[4];
    float* yo = (float*)d_out;

    dim3 grid(DIN / 16, B_);   // (24, 64) = 1536 blocks, 16 chains/block
    dim3 block(256);           // 4 waves; 24 waves/CU resident (grid-exact)
    ssm_tlp<<<grid, block, 0, stream>>>(x, dA, dB, C, D, yo);
}

// Round 10
// 141.341 us; speedup vs baseline: 1.0266x; 1.0266x over previous
//
#include <hip/hip_runtime.h>

// Selective scan, fp32.  x:(B,d,L) dA/dB:(B,d,L,n) C:(B,n,L) D:(d,) -> y:(B,d,L)
// B=64 d=384 L=197 n=16.
//
// Round-10: DMA-pinned prefetch (R8) x high TLP. 8-step tiles, 256-thread
// blocks (4 waves x 4 chains), wave-private double-buffered LDS, counted
// vmcnt so one 5-op tile (~4.25KB/wave) is ALWAYS in flight -> 12 waves/CU
// (vs R8's 6) with the same HW-guaranteed bytes outstanding per CU.
// Cs kept LINEAR (Cs[n*197+t]): conflict-free staging writes AND reads
// (stride 197 = 5 mod 32), killing R8's 9.2M conflict cycles.

#define B_   64
#define DIN  384
#define L_   197
#define N_   16
#define LN   (L_ * N_)      // 3152 floats per chain per array
#define TS   8              // steps per tile
#define NFT  24             // full tiles t=0..191
#define TT0  189            // tail window 189..196, compute j=3..7
#define BUFW 1120           // floats per buffer: A[0,520) B[528,1048) X[1056,1120)
#define WAVEW (2*BUFW)      // 2240 floats per wave
#define CS_OFF (4*WAVEW)    // 8960
#define LDSW (CS_OFF + LN)  // 12112 floats = 48448 B -> 3 blocks/CU

typedef unsigned int u32as1 __attribute__((address_space(1)));
typedef unsigned int u32as3 __attribute__((address_space(3)));

__device__ __forceinline__ void gll16(const float* g, float* l) {
    __builtin_amdgcn_global_load_lds((const u32as1*)g, (u32as3*)l, 16, 0, 0);
}
__device__ __forceinline__ void gll4(const float* g, float* l) {
    __builtin_amdgcn_global_load_lds((const u32as1*)g, (u32as3*)l, 4, 0, 0);
}

template<int CTRL>
__device__ __forceinline__ float dppadd(float p) {
    return p + __int_as_float(__builtin_amdgcn_update_dpp(
        0, __float_as_int(p), CTRL, 0xF, 0xF, true));
}
// sum over 16 lanes (one row), result in all 16
__device__ __forceinline__ float sum16(float p) {
    p = dppadd<0xB1>(p);    // quad_perm xor1
    p = dppadd<0x4E>(p);    // quad_perm xor2
    p = dppadd<0x141>(p);   // row_half_mirror: quad<->quad
    p = dppadd<0x140>(p);   // row_mirror: 8-half<->8-half
    return p;
}

__global__ __launch_bounds__(256, 3)
void ssm_dma12(const float* __restrict__ x, const float* __restrict__ dA,
               const float* __restrict__ dB, const float* __restrict__ C,
               const float* __restrict__ D, float* __restrict__ y)
{
    __shared__ __align__(16) float lds[LDSW];

    const int tid = threadIdx.x;
    const int b   = blockIdx.y;
    const int d0  = blockIdx.x * 16;

    // Cs LINEAR: Cs[n*197 + t] = C[b,n,t]; straight copy, conflict-free.
    const float* Cg = C + (size_t)b * LN;
    for (int i = tid; i < LN; i += 256) lds[CS_OFF + i] = Cg[i];
    __syncthreads();

    const int wav  = tid >> 6;
    const int lane = tid & 63;
    const int g    = lane >> 4;        // chain within wave (4/wave)
    const int n    = lane & 15;        // state index

    const int wc   = wav * 4;          // wave's first chain within block
    const int bd0  = b * DIN + d0;

    // per-lane DMA sources (float pointers)
    const float* srcA01 = dA + (size_t)(bd0 + wc + (lane >> 5)) * LN + (lane & 31) * 4;
    const float* srcA23 = srcA01 + 2 * (size_t)LN;
    const float* srcB01 = dB + (size_t)(bd0 + wc + (lane >> 5)) * LN + (lane & 31) * 4;
    const float* srcB23 = srcB01 + 2 * (size_t)LN;
    const int lm = lane < 32 ? lane : 31;
    const float* srcX = x + (size_t)(bd0 + wc + (lm >> 3)) * L_ + (lm & 7);

    float* wl = lds + wav * WAVEW;     // wave-private LDS region

    float*       Yrow = y + (size_t)(bd0 + wc + g) * L_;
    const float  Dd   = D[d0 + wc + g];
    const float* CsL  = lds + CS_OFF + n * L_;
    const int    aoff = (g >> 1) * 264 + (g & 1) * 128 + n;

#define STAGE(bsel, t0) do { \
    float* _d = wl + (bsel) * BUFW; \
    gll16(srcA01 + (t0) * 16, _d +   0); \
    gll16(srcA23 + (t0) * 16, _d + 264); \
    gll16(srcB01 + (t0) * 16, _d + 528); \
    gll16(srcB23 + (t0) * 16, _d + 792); \
    gll4 (srcX   + (t0),      _d + 1056); \
} while (0)

#define STEP(bufp, t0, j, J0) do { \
    if ((j) >= (J0)) { \
        const float _a  = (bufp)[aoff + (j) * 16]; \
        const float _bb = (bufp)[528 + aoff + (j) * 16]; \
        const float _xv = (bufp)[1056 + g * 8 + (j)]; \
        h = fmaf(_a, h, _bb * _xv); \
        float _p = h * CsL[(t0) + (j)]; \
        _p = sum16(_p); \
        const float _yt = fmaf(_xv, Dd, _p); \
        ys = (n == (j)) ? _yt : ys; \
    } \
} while (0)

#define TILE(bsel, t0, J0) do { \
    const float* _bp = wl + (bsel) * BUFW; \
    STEP(_bp, t0, 0, J0); STEP(_bp, t0, 1, J0); \
    STEP(_bp, t0, 2, J0); STEP(_bp, t0, 3, J0); \
    STEP(_bp, t0, 4, J0); STEP(_bp, t0, 5, J0); \
    STEP(_bp, t0, 6, J0); STEP(_bp, t0, 7, J0); \
} while (0)

    float h = 0.f, ys = 0.f;

    STAGE(0, 0);
    STAGE(1, TS);
    asm volatile("s_waitcnt vmcnt(5)" ::: "memory");   // tile0 resident
    TILE(0, 0, 0);
    if (n < 8) Yrow[n] = ys;
    STAGE(0, 2 * TS);                                   // stage tile 2

#pragma unroll 1
    for (int k = 1; k < NFT; ++k) {
        // drain through stage(k); leaves store(k-1) + stage(k+1) in flight
        asm volatile("s_waitcnt vmcnt(6)" ::: "memory");
        const int t0 = k * TS;
        TILE(k & 1, t0, 0);
        if (n < 8) Yrow[t0 + n] = ys;
        if (k < NFT - 1) {
            const int tn = (k + 2 < NFT) ? (k + 2) * TS : TT0;
            STAGE(k & 1, tn);       // stage s=k+2 into the buf just consumed
        }
    }
    // tail: staged into buf (24&1)=0 at t0=189; compute j=3..7 (t=192..196)
    asm volatile("s_waitcnt vmcnt(1)" ::: "memory");
    TILE(0, TT0, 3);
    if (n >= 3 && n < 8) Yrow[TT0 + n] = ys;

#undef TILE
#undef STEP
#undef STAGE
}

extern "C" void kernel_launch(void* const* d_in, const int* in_sizes, int n_in,
                              void* d_out, int out_size, void* d_ws, size_t ws_size,
                              hipStream_t stream) {
    const float* x  = (const float*)d_in[0];
    const float* dA = (const float*)d_in[1];
    const float* dB = (const float*)d_in[2];
    const float* C  = (const float*)d_in[3];
    const float* D  = (const float*)d_in[4];
    float* yo = (float*)d_out;

    dim3 grid(DIN / 16, B_);   // (24, 64) = 1536 blocks; 3 resident/CU = 12 waves/CU
    dim3 block(256);           // 4 waves x 4 chains
    ssm_dma12<<<grid, block, 0, stream>>>(x, dA, dB, C, D, yo);
}

// Round 11
// 137.475 us; speedup vs baseline: 1.0554x; 1.0281x over previous
//
#include <hip/hip_runtime.h>

// Selective scan, fp32.  x:(B,d,L) dA/dB:(B,d,L,n) C:(B,n,L) D:(d,) -> y:(B,d,L)
// B=64 d=384 L=197 n=16.
//
// Round-11: R10 base (DMA-pinned prefetch, 12 waves/CU, 141.3us) + ONE change:
// dB is loaded NON-TEMPORAL (cpol NT bit in global_load_lds aux) so it never
// allocates in L2/L3. Theory: L3 random-replacement gives both 310MB streams
// ~50% hits (FETCH=320MB of 640MB); excluding dB lets L3 retain dA (+x) at
// ~78% hits, moving work off the oversubscribed L3 path onto idle HBM BW.

#define B_   64
#define DIN  384
#define L_   197
#define N_   16
#define LN   (L_ * N_)      // 3152 floats per chain per array
#define TS   8              // steps per tile
#define NFT  24             // full tiles t=0..191
#define TT0  189            // tail window 189..196, compute j=3..7
#define BUFW 1120           // floats per buffer: A[0,520) B[528,1048) X[1056,1120)
#define WAVEW (2*BUFW)      // 2240 floats per wave
#define CS_OFF (4*WAVEW)    // 8960
#define LDSW (CS_OFF + LN)  // 12112 floats = 48448 B -> 3 blocks/CU

typedef unsigned int u32as1 __attribute__((address_space(1)));
typedef unsigned int u32as3 __attribute__((address_space(3)));

__device__ __forceinline__ void gll16(const float* g, float* l) {
    __builtin_amdgcn_global_load_lds((const u32as1*)g, (u32as3*)l, 16, 0, 0);
}
__device__ __forceinline__ void gll16nt(const float* g, float* l) {
    // aux bit1 = NT on gfx940+ (CPol::SLC slot): no-allocate in L2/L3
    __builtin_amdgcn_global_load_lds((const u32as1*)g, (u32as3*)l, 16, 0, 2);
}
__device__ __forceinline__ void gll4(const float* g, float* l) {
    __builtin_amdgcn_global_load_lds((const u32as1*)g, (u32as3*)l, 4, 0, 0);
}

template<int CTRL>
__device__ __forceinline__ float dppadd(float p) {
    return p + __int_as_float(__builtin_amdgcn_update_dpp(
        0, __float_as_int(p), CTRL, 0xF, 0xF, true));
}
// sum over 16 lanes (one row), result in all 16
__device__ __forceinline__ float sum16(float p) {
    p = dppadd<0xB1>(p);    // quad_perm xor1
    p = dppadd<0x4E>(p);    // quad_perm xor2
    p = dppadd<0x141>(p);   // row_half_mirror: quad<->quad
    p = dppadd<0x140>(p);   // row_mirror: 8-half<->8-half
    return p;
}

__global__ __launch_bounds__(256, 3)
void ssm_nt(const float* __restrict__ x, const float* __restrict__ dA,
            const float* __restrict__ dB, const float* __restrict__ C,
            const float* __restrict__ D, float* __restrict__ y)
{
    __shared__ __align__(16) float lds[LDSW];

    const int tid = threadIdx.x;
    const int b   = blockIdx.y;
    const int d0  = blockIdx.x * 16;

    // Cs LINEAR: Cs[n*197 + t] = C[b,n,t]; straight copy, conflict-free.
    const float* Cg = C + (size_t)b * LN;
    for (int i = tid; i < LN; i += 256) lds[CS_OFF + i] = Cg[i];
    __syncthreads();

    const int wav  = tid >> 6;
    const int lane = tid & 63;
    const int g    = lane >> 4;        // chain within wave (4/wave)
    const int n    = lane & 15;        // state index

    const int wc   = wav * 4;          // wave's first chain within block
    const int bd0  = b * DIN + d0;

    // per-lane DMA sources (float pointers)
    const float* srcA01 = dA + (size_t)(bd0 + wc + (lane >> 5)) * LN + (lane & 31) * 4;
    const float* srcA23 = srcA01 + 2 * (size_t)LN;
    const float* srcB01 = dB + (size_t)(bd0 + wc + (lane >> 5)) * LN + (lane & 31) * 4;
    const float* srcB23 = srcB01 + 2 * (size_t)LN;
    const int lm = lane < 32 ? lane : 31;
    const float* srcX = x + (size_t)(bd0 + wc + (lm >> 3)) * L_ + (lm & 7);

    float* wl = lds + wav * WAVEW;     // wave-private LDS region

    float*       Yrow = y + (size_t)(bd0 + wc + g) * L_;
    const float  Dd   = D[d0 + wc + g];
    const float* CsL  = lds + CS_OFF + n * L_;
    const int    aoff = (g >> 1) * 264 + (g & 1) * 128 + n;

#define STAGE(bsel, t0) do { \
    float* _d = wl + (bsel) * BUFW; \
    gll16  (srcA01 + (t0) * 16, _d +   0); \
    gll16  (srcA23 + (t0) * 16, _d + 264); \
    gll16nt(srcB01 + (t0) * 16, _d + 528); \
    gll16nt(srcB23 + (t0) * 16, _d + 792); \
    gll4   (srcX   + (t0),      _d + 1056); \
} while (0)

#define STEP(bufp, t0, j, J0) do { \
    if ((j) >= (J0)) { \
        const float _a  = (bufp)[aoff + (j) * 16]; \
        const float _bb = (bufp)[528 + aoff + (j) * 16]; \
        const float _xv = (bufp)[1056 + g * 8 + (j)]; \
        h = fmaf(_a, h, _bb * _xv); \
        float _p = h * CsL[(t0) + (j)]; \
        _p = sum16(_p); \
        const float _yt = fmaf(_xv, Dd, _p); \
        ys = (n == (j)) ? _yt : ys; \
    } \
} while (0)

#define TILE(bsel, t0, J0) do { \
    const float* _bp = wl + (bsel) * BUFW; \
    STEP(_bp, t0, 0, J0); STEP(_bp, t0, 1, J0); \
    STEP(_bp, t0, 2, J0); STEP(_bp, t0, 3, J0); \
    STEP(_bp, t0, 4, J0); STEP(_bp, t0, 5, J0); \
    STEP(_bp, t0, 6, J0); STEP(_bp, t0, 7, J0); \
} while (0)

    float h = 0.f, ys = 0.f;

    STAGE(0, 0);
    STAGE(1, TS);
    asm volatile("s_waitcnt vmcnt(5)" ::: "memory");   // tile0 resident
    TILE(0, 0, 0);
    if (n < 8) Yrow[n] = ys;
    STAGE(0, 2 * TS);                                   // stage tile 2

#pragma unroll 1
    for (int k = 1; k < NFT; ++k) {
        // drain through stage(k); leaves store(k-1) + stage(k+1) in flight
        asm volatile("s_waitcnt vmcnt(6)" ::: "memory");
        const int t0 = k * TS;
        TILE(k & 1, t0, 0);
        if (n < 8) Yrow[t0 + n] = ys;
        if (k < NFT - 1) {
            const int tn = (k + 2 < NFT) ? (k + 2) * TS : TT0;
            STAGE(k & 1, tn);       // stage s=k+2 into the buf just consumed
        }
    }
    // tail: staged into buf (24&1)=0 at t0=189; compute j=3..7 (t=192..196)
    asm volatile("s_waitcnt vmcnt(1)" ::: "memory");
    TILE(0, TT0, 3);
    if (n >= 3 && n < 8) Yrow[TT0 + n] = ys;

#undef TILE
#undef STEP
#undef STAGE
}

extern "C" void kernel_launch(void* const* d_in, const int* in_sizes, int n_in,
                              void* d_out, int out_size, void* d_ws, size_t ws_size,
                              hipStream_t stream) {
    const float* x  = (const float*)d_in[0];
    const float* dA = (const float*)d_in[1];
    const float* dB = (const float*)d_in[2];
    const float* C  = (const float*)d_in[3];
    const float* D  = (const float*)d_in[4];
    float* yo = (float*)d_out;

    dim3 grid(DIN / 16, B_);   // (24, 64) = 1536 blocks; 3 resident/CU = 12 waves/CU
    dim3 block(256);           // 4 waves x 4 chains
    ssm_nt<<<grid, block, 0, stream>>>(x, dA, dB, C, D, yo);
}

// Round 12
// 136.300 us; speedup vs baseline: 1.0645x; 1.0086x over previous
//
#include <hip/hip_runtime.h>

// Selective scan, fp32.  x:(B,d,L) dA/dB:(B,d,L,n) C:(B,n,L) D:(d,) -> y:(B,d,L)
// B=64 d=384 L=197 n=16.
//
// Round-12: R11 base + ONE change: NT (non-temporal, no-allocate) on BOTH
// dA and dB streams (R11 had it on dB only; dur 141.3->137.5, FETCH 320->332).
// Full bypass should push all ~620MB of single-use stream onto the HBM read
// path (fill kernel proves 6.6 TB/s headroom) instead of splitting with an
// oversubscribed L3 at ~50% hit rate.

#define B_   64
#define DIN  384
#define L_   197
#define N_   16
#define LN   (L_ * N_)      // 3152 floats per chain per array
#define TS   8              // steps per tile
#define NFT  24             // full tiles t=0..191
#define TT0  189            // tail window 189..196, compute j=3..7
#define BUFW 1120           // floats per buffer: A[0,520) B[528,1048) X[1056,1120)
#define WAVEW (2*BUFW)      // 2240 floats per wave
#define CS_OFF (4*WAVEW)    // 8960
#define LDSW (CS_OFF + LN)  // 12112 floats = 48448 B -> 3 blocks/CU

typedef unsigned int u32as1 __attribute__((address_space(1)));
typedef unsigned int u32as3 __attribute__((address_space(3)));

__device__ __forceinline__ void gll16nt(const float* g, float* l) {
    // aux bit1 = NT (CPol SLC slot on gfx940+): non-temporal, no-allocate
    __builtin_amdgcn_global_load_lds((const u32as1*)g, (u32as3*)l, 16, 0, 2);
}
__device__ __forceinline__ void gll4(const float* g, float* l) {
    __builtin_amdgcn_global_load_lds((const u32as1*)g, (u32as3*)l, 4, 0, 0);
}

template<int CTRL>
__device__ __forceinline__ float dppadd(float p) {
    return p + __int_as_float(__builtin_amdgcn_update_dpp(
        0, __float_as_int(p), CTRL, 0xF, 0xF, true));
}
// sum over 16 lanes (one row), result in all 16
__device__ __forceinline__ float sum16(float p) {
    p = dppadd<0xB1>(p);    // quad_perm xor1
    p = dppadd<0x4E>(p);    // quad_perm xor2
    p = dppadd<0x141>(p);   // row_half_mirror: quad<->quad
    p = dppadd<0x140>(p);   // row_mirror: 8-half<->8-half
    return p;
}

__global__ __launch_bounds__(256, 3)
void ssm_nt2(const float* __restrict__ x, const float* __restrict__ dA,
             const float* __restrict__ dB, const float* __restrict__ C,
             const float* __restrict__ D, float* __restrict__ y)
{
    __shared__ __align__(16) float lds[LDSW];

    const int tid = threadIdx.x;
    const int b   = blockIdx.y;
    const int d0  = blockIdx.x * 16;

    // Cs LINEAR: Cs[n*197 + t] = C[b,n,t]; straight copy, conflict-free.
    const float* Cg = C + (size_t)b * LN;
    for (int i = tid; i < LN; i += 256) lds[CS_OFF + i] = Cg[i];
    __syncthreads();

    const int wav  = tid >> 6;
    const int lane = tid & 63;
    const int g    = lane >> 4;        // chain within wave (4/wave)
    const int n    = lane & 15;        // state index

    const int wc   = wav * 4;          // wave's first chain within block
    const int bd0  = b * DIN + d0;

    // per-lane DMA sources (float pointers)
    const float* srcA01 = dA + (size_t)(bd0 + wc + (lane >> 5)) * LN + (lane & 31) * 4;
    const float* srcA23 = srcA01 + 2 * (size_t)LN;
    const float* srcB01 = dB + (size_t)(bd0 + wc + (lane >> 5)) * LN + (lane & 31) * 4;
    const float* srcB23 = srcB01 + 2 * (size_t)LN;
    const int lm = lane < 32 ? lane : 31;
    const float* srcX = x + (size_t)(bd0 + wc + (lm >> 3)) * L_ + (lm & 7);

    float* wl = lds + wav * WAVEW;     // wave-private LDS region

    float*       Yrow = y + (size_t)(bd0 + wc + g) * L_;
    const float  Dd   = D[d0 + wc + g];
    const float* CsL  = lds + CS_OFF + n * L_;
    const int    aoff = (g >> 1) * 264 + (g & 1) * 128 + n;

#define STAGE(bsel, t0) do { \
    float* _d = wl + (bsel) * BUFW; \
    gll16nt(srcA01 + (t0) * 16, _d +   0); \
    gll16nt(srcA23 + (t0) * 16, _d + 264); \
    gll16nt(srcB01 + (t0) * 16, _d + 528); \
    gll16nt(srcB23 + (t0) * 16, _d + 792); \
    gll4   (srcX   + (t0),      _d + 1056); \
} while (0)

#define STEP(bufp, t0, j, J0) do { \
    if ((j) >= (J0)) { \
        const float _a  = (bufp)[aoff + (j) * 16]; \
        const float _bb = (bufp)[528 + aoff + (j) * 16]; \
        const float _xv = (bufp)[1056 + g * 8 + (j)]; \
        h = fmaf(_a, h, _bb * _xv); \
        float _p = h * CsL[(t0) + (j)]; \
        _p = sum16(_p); \
        const float _yt = fmaf(_xv, Dd, _p); \
        ys = (n == (j)) ? _yt : ys; \
    } \
} while (0)

#define TILE(bsel, t0, J0) do { \
    const float* _bp = wl + (bsel) * BUFW; \
    STEP(_bp, t0, 0, J0); STEP(_bp, t0, 1, J0); \
    STEP(_bp, t0, 2, J0); STEP(_bp, t0, 3, J0); \
    STEP(_bp, t0, 4, J0); STEP(_bp, t0, 5, J0); \
    STEP(_bp, t0, 6, J0); STEP(_bp, t0, 7, J0); \
} while (0)

    float h = 0.f, ys = 0.f;

    STAGE(0, 0);
    STAGE(1, TS);
    asm volatile("s_waitcnt vmcnt(5)" ::: "memory");   // tile0 resident
    TILE(0, 0, 0);
    if (n < 8) Yrow[n] = ys;
    STAGE(0, 2 * TS);                                   // stage tile 2

#pragma unroll 1
    for (int k = 1; k < NFT; ++k) {
        // drain through stage(k); leaves store(k-1) + stage(k+1) in flight
        asm volatile("s_waitcnt vmcnt(6)" ::: "memory");
        const int t0 = k * TS;
        TILE(k & 1, t0, 0);
        if (n < 8) Yrow[t0 + n] = ys;
        if (k < NFT - 1) {
            const int tn = (k + 2 < NFT) ? (k + 2) * TS : TT0;
            STAGE(k & 1, tn);       // stage s=k+2 into the buf just consumed
        }
    }
    // tail: staged into buf (24&1)=0 at t0=189; compute j=3..7 (t=192..196)
    asm volatile("s_waitcnt vmcnt(1)" ::: "memory");
    TILE(0, TT0, 3);
    if (n >= 3 && n < 8) Yrow[TT0 + n] = ys;

#undef TILE
#undef STEP
#undef STAGE
}

extern "C" void kernel_launch(void* const* d_in, const int* in_sizes, int n_in,
                              void* d_out, int out_size, void* d_ws, size_t ws_size,
                              hipStream_t stream) {
    const float* x  = (const float*)d_in[0];
    const float* dA = (const float*)d_in[1];
    const float* dB = (const float*)d_in[2];
    const float* C  = (const float*)d_in[3];
    const float* D  = (const float*)d_in[4];
    float* yo = (float*)d_out;

    dim3 grid(DIN / 16, B_);   // (24, 64) = 1536 blocks; 3 resident/CU = 12 waves/CU
    dim3 block(256);           // 4 waves x 4 chains
    ssm_nt2<<<grid, block, 0, stream>>>(x, dA, dB, C, D, yo);
}